// Round 9
// baseline (282.608 us; speedup 1.0000x reference)
//
#include <hip/hip_runtime.h>

// Attention_73375221285454: fused MHA block on MI355X (gfx950)
// B=4 N=2048 D=768 H=12 DH=64. fp32 in/out, bf16 MFMA internally.
// Round 9: compact BEFORE the GEMMs. Valid x rows gathered+converted into
// xc (zero-padded to 128); QKV GEMM row-tiles beyond cnpad exit -> ~half the
// GEMM work; Q/K/V produced pre-compacted (k_gather deleted). Masked-row
// output = xmean@Wv@Wo by linearity (fp32 GEMV chain; vmeanA/B, k_fill,
// k_convx deleted). Out-GEMM on compacted Ao with idx-scatter epilogue +
// k_fillout broadcast. GEMM sync structure = round 8 (unchanged).

#define B_ 4
#define N_ 2048
#define D_ 768
#define H_ 12
#define DH_ 64
#define CSC_ 0.18033688011112042f  // SCALE * log2(e)

typedef __attribute__((ext_vector_type(8))) short bf8_t;   // 8 bf16 (MFMA A/B frag)
typedef __attribute__((ext_vector_type(4))) float f4_t;    // 16x16 C/D frag
typedef __attribute__((ext_vector_type(16))) float f16v;   // 32x32 C/D frag
typedef __attribute__((ext_vector_type(4))) int i4_t;

__device__ __forceinline__ short f2b(float f) {            // fp32 -> bf16 RNE
  union { float f; unsigned u; } v; v.f = f;
  unsigned r = v.u + 0x7FFFu + ((v.u >> 16) & 1u);
  return (short)(r >> 16);
}
__device__ __forceinline__ unsigned cvtpk(float lo, float hi) {
  unsigned r;
  asm("v_cvt_pk_bf16_f32 %0, %1, %2" : "=v"(r) : "v"(lo), "v"(hi));
  return r;
}
__device__ __forceinline__ void plswap(unsigned& a, unsigned& b) {
  asm("v_permlane32_swap_b32 %0, %1" : "+v"(a), "+v"(b));
}
__device__ __forceinline__ float max3f(float a, float b, float c) {
  float r;
  asm("v_max3_f32 %0, %1, %2, %3" : "=v"(r) : "v"(a), "v"(b), "v"(c));
  return r;
}

#define GLOAD_LDS16(gp, lp)                                                       \
  __builtin_amdgcn_global_load_lds(                                               \
      (const __attribute__((address_space(1))) void*)(gp),                        \
      (__attribute__((address_space(3))) void*)(lp), 16, 0, 0)

// ---------------- per-batch valid-index list (order-preserving scan) ----------------
__global__ __launch_bounds__(256) void k_maskidx(const int* __restrict__ xmask,
                                                 int* __restrict__ idx,
                                                 int* __restrict__ cnt) {
  int b = blockIdx.x, t = threadIdx.x;
  const int* mp = xmask + b * N_;
  int loc[8], c = 0;
#pragma unroll
  for (int j = 0; j < 8; ++j) {
    int n = t * 8 + j;
    if (mp[n]) loc[c++] = n;
  }
  __shared__ int sc[256];
  sc[t] = c;
  __syncthreads();
  for (int off = 1; off < 256; off <<= 1) {
    int v = (t >= off) ? sc[t - off] : 0;
    __syncthreads();
    sc[t] += v;
    __syncthreads();
  }
  int base = sc[t] - c;
  int* op = idx + b * N_;
  for (int j = 0; j < c; ++j) op[base + j] = loc[j];
  if (t == 255) cnt[b] = sc[255];
}

// ------- xsum stage A: per-(b,chunk-of-32-rows) column sums of x (fp32) -------
__global__ __launch_bounds__(256) void k_xsumA(const float* __restrict__ x,
                                               float* __restrict__ xpart) {
  int b = blockIdx.y, ch = blockIdx.x, t = threadIdx.x;
  const float* xp = x + ((size_t)b * N_ + ch * 32) * D_;
  float a0 = 0, a1 = 0, a2 = 0;
  for (int r = 0; r < 32; ++r) {
    const float* rp = xp + (size_t)r * D_;
    a0 += rp[t]; a1 += rp[t + 256]; a2 += rp[t + 512];
  }
  float* op = xpart + ((size_t)b * 64 + ch) * D_;
  op[t] = a0; op[t + 256] = a1; op[t + 512] = a2;
}

// ------- gather valid x rows -> compacted bf16 xc (zero rows beyond cnt) -------
__global__ __launch_bounds__(256) void k_gatherx(const float* __restrict__ x,
                                                 const int* __restrict__ idx,
                                                 const int* __restrict__ cnt,
                                                 short* __restrict__ xc) {
  int b = blockIdx.y;
  int j = blockIdx.x * 8 + (threadIdx.x >> 5);
  int cn = cnt[b];
  int l5 = threadIdx.x & 31;
  short* op = xc + ((size_t)b * N_ + j) * D_;
  if (j < cn) {
    int n = idx[b * N_ + j];
    const float* rp = x + ((size_t)b * N_ + n) * D_;
#pragma unroll
    for (int it = 0; it < 3; ++it) {
      int c = (l5 + it * 32) * 8;
      float4 v0 = *(const float4*)(rp + c);
      float4 v1 = *(const float4*)(rp + c + 4);
      bf8_t o;
      o[0] = f2b(v0.x); o[1] = f2b(v0.y); o[2] = f2b(v0.z); o[3] = f2b(v0.w);
      o[4] = f2b(v1.x); o[5] = f2b(v1.y); o[6] = f2b(v1.z); o[7] = f2b(v1.w);
      *(bf8_t*)(op + c) = o;
    }
  } else {
    const bf8_t zz = {0, 0, 0, 0, 0, 0, 0, 0};
#pragma unroll
    for (int it = 0; it < 3; ++it) {
      int c = (l5 + it * 32) * 8;
      *(bf8_t*)(op + c) = zz;
    }
  }
}

// ------- prep: transpose weights fp32->bf16 into B^T layout; Wq pre-scaled -------
__global__ __launch_bounds__(256) void k_wtrans(const float* __restrict__ Wq,
                                                const float* __restrict__ Wk,
                                                const float* __restrict__ Wv,
                                                const float* __restrict__ Wo,
                                                short* __restrict__ WqkvT,
                                                short* __restrict__ WoT) {
  int z = blockIdx.z;
  const float* W = (z == 0) ? Wq : (z == 1) ? Wk : (z == 2) ? Wv : Wo;
  short* dst = (z < 3) ? (WqkvT + (size_t)z * D_ * D_) : WoT;
  float sc = (z == 0) ? CSC_ : 1.f;
  __shared__ float T[64][65];
  int r0 = blockIdx.y * 64, c0 = blockIdx.x * 64;
  int tr = threadIdx.x >> 6, tc = threadIdx.x & 63;
#pragma unroll
  for (int i = 0; i < 16; ++i) {
    int r = tr + i * 4;
    T[r][tc] = W[(size_t)(r0 + r) * D_ + c0 + tc];
  }
  __syncthreads();
#pragma unroll
  for (int i = 0; i < 16; ++i) {
    int r = tr + i * 4;
    dst[(size_t)(c0 + r) * D_ + r0 + tc] = f2b(T[tc][r] * sc);
  }
}

// ------- GEMM (r8 structure + compaction exit): C = A[M x K] * BT[Ncol x K]^T -------
// 128x128 tile, BK=64, 4 waves, dbuf gload_lds, counted vmcnt, XOR-swizzle.
// Row-tiles beyond this batch's cnpad (cnt padded to 128) exit immediately.
// MODE 0: scatter epilogue to compacted Qb/Kc/Vc. MODE 1: fp32 out scattered
// through idx (valid rows only).
template <int MODE>
__global__ __launch_bounds__(256) void k_gemm(const short* __restrict__ A,
                                              const short* __restrict__ BT, int K,
                                              short* __restrict__ Qb, short* __restrict__ Kb,
                                              short* __restrict__ Vb,
                                              float* __restrict__ Cout, int ldc,
                                              const int* __restrict__ cnt,
                                              const int* __restrict__ idx) {
  __shared__ short As[2][128 * 64];
  __shared__ short Bs[2][128 * 64];
  // T1: bijective XCD swizzle (nwg % 8 == 0 for both launches)
  int gx = gridDim.x;
  int nwg = gx * gridDim.y;
  int flat = blockIdx.y * gx + blockIdx.x;
  int cpx = nwg >> 3;
  int swzb = (flat & 7) * cpx + (flat >> 3);
  int row0 = (swzb / gx) * 128, col0 = (swzb % gx) * 128;

  int bb = row0 >> 11;
  int cn = cnt[bb];
  int cnpad = (cn + 127) & ~127;
  if ((row0 & 2047) >= cnpad) return;  // masked-row tile: nothing to do

  int tid = threadIdx.x, lane = tid & 63, w = tid >> 6;
  int wr = w >> 1, wc = w & 1;
  int lr = lane & 15, lhi = lane >> 4;
  f4_t acc[4][4];
#pragma unroll
  for (int mi = 0; mi < 4; ++mi)
#pragma unroll
    for (int ni = 0; ni < 4; ++ni) acc[mi][ni] = (f4_t){0.f, 0.f, 0.f, 0.f};

  int sub = lane >> 3;
  int scb = ((lane & 7) * 16) ^ (sub << 4);  // pre-swizzled global byte col
  auto STAGE = [&](int k0, int buf) {
    char* ab = (char*)As[buf] + (w << 12);
    char* bb2 = (char*)Bs[buf] + (w << 12);
#pragma unroll
    for (int i = 0; i < 4; ++i) {
      int r = 32 * w + 8 * i + sub;
      GLOAD_LDS16((const char*)(A + (size_t)(row0 + r) * K + k0) + scb, ab + (i << 10));
      GLOAD_LDS16((const char*)(BT + (size_t)(col0 + r) * K + k0) + scb, bb2 + (i << 10));
    }
  };

  STAGE(0, 0);

  int nt = K / 64;
  for (int t = 0; t < nt; ++t) {
    int cur = t & 1;
    if (t + 1 < nt) {
      STAGE((t + 1) * 64, cur ^ 1);  // 8 loads in flight across barriers (T4)
      asm volatile("s_waitcnt vmcnt(8)" ::: "memory");
    } else {
      asm volatile("s_waitcnt vmcnt(0)" ::: "memory");
    }
    __builtin_amdgcn_sched_barrier(0);
    __builtin_amdgcn_s_barrier();

    const char* Ac = (const char*)As[cur];
    const char* Bc = (const char*)Bs[cur];
    int rsw = (lr & 7) << 4;
#pragma unroll
    for (int kc = 0; kc < 2; ++kc) {
      bf8_t av[4], bv[4];
#pragma unroll
      for (int mi = 0; mi < 4; ++mi) {
        int row = 64 * wr + 16 * mi + lr;
        av[mi] = *(const bf8_t*)(Ac + row * 128 + ((64 * kc + 16 * lhi) ^ rsw));
      }
#pragma unroll
      for (int ni = 0; ni < 4; ++ni) {
        int row = 64 * wc + 16 * ni + lr;
        bv[ni] = *(const bf8_t*)(Bc + row * 128 + ((64 * kc + 16 * lhi) ^ rsw));
      }
#pragma unroll
      for (int mi = 0; mi < 4; ++mi)
#pragma unroll
        for (int ni = 0; ni < 4; ++ni)
          acc[mi][ni] = __builtin_amdgcn_mfma_f32_16x16x32_bf16(av[mi], bv[ni], acc[mi][ni], 0, 0, 0);
    }
    __builtin_amdgcn_sched_barrier(0);
    __builtin_amdgcn_s_barrier();
  }

#pragma unroll
  for (int mi = 0; mi < 4; ++mi)
#pragma unroll
    for (int ni = 0; ni < 4; ++ni)
#pragma unroll
      for (int r = 0; r < 4; ++r) {
        int row = row0 + 64 * wr + 16 * mi + 4 * lhi + r;
        int col = col0 + 64 * wc + 16 * ni + lr;
        float v = acc[mi][ni][r];
        if (MODE == 0) {
          int which = col / 768;
          int cc2 = col - which * 768;
          int h = cc2 >> 6, dh = cc2 & 63;
          int b = row >> 11, n = row & 2047;  // n = compacted index
          size_t dst = (((size_t)(b * H_ + h)) * N_ + n) * DH_ + dh;
          short bv2 = f2b(v);
          if (which == 0) Qb[dst] = bv2;
          else if (which == 1) Kb[dst] = bv2;
          else Vb[dst] = bv2;
        } else {
          int j = row & 2047;
          if (j < cn) {
            int n = idx[(row & ~2047) + j];
            Cout[((size_t)(row & ~2047) + n) * ldc + col] = v;
          }
        }
      }
}

// ---------------- Vc[bh][j][dh] -> Vtc[bh][dh][j] (compacted; skip past cnpad) ----------------
__global__ __launch_bounds__(256) void k_vtrans(const short* __restrict__ V,
                                                const int* __restrict__ cnt,
                                                short* __restrict__ Vt) {
  int bh = blockIdx.y, b = bh / H_;
  int n0 = blockIdx.x * 64;
  int cn = cnt[b];
  int cnpad = (cn + 127) & ~127;
  if (n0 >= cnpad) return;
  __shared__ short T[64][72];
  int tr = threadIdx.x >> 6, tc = threadIdx.x & 63;
  const short* Vp = V + (size_t)bh * N_ * DH_;
  short* Vtp = Vt + (size_t)bh * DH_ * N_;
#pragma unroll
  for (int i = 0; i < 16; ++i) {
    int r = tr + i * 4;
    T[r][tc] = Vp[(size_t)(n0 + r) * DH_ + tc];
  }
  __syncthreads();
#pragma unroll
  for (int i = 0; i < 16; ++i) {
    int r = tr + i * 4;
    Vtp[(size_t)r * N_ + n0 + tc] = T[tc][r];
  }
}

// ------- vmean[b] = (xsum[b]/2048) @ Wv  (fp32 GEMV, 3 col-chunks x 4 batches) -------
__global__ __launch_bounds__(256) void k_vmean(const float* __restrict__ xpart,
                                               const float* __restrict__ Wv,
                                               float* __restrict__ vmeanG) {
  int b = blockIdx.y, cc = blockIdx.x, t = threadIdx.x;
  __shared__ float xm[768];
  for (int c = t; c < 768; c += 256) {
    float s = 0;
    for (int ch = 0; ch < 64; ++ch) s += xpart[((size_t)b * 64 + ch) * D_ + c];
    xm[c] = s * (1.f / 2048.f);
  }
  __syncthreads();
  int col = cc * 256 + t;
  float acc = 0;
#pragma unroll 4
  for (int k = 0; k < 768; ++k) acc += xm[k] * Wv[(size_t)k * D_ + col];
  vmeanG[b * D_ + col] = acc;
}

// ------- outrow[b] = vmean[b] @ Wo  (fp32 GEMV) -------
__global__ __launch_bounds__(256) void k_outrow(const float* __restrict__ vmeanG,
                                                const float* __restrict__ Wo,
                                                float* __restrict__ outrowG) {
  int b = blockIdx.y, cc = blockIdx.x, t = threadIdx.x;
  __shared__ float vm[768];
  for (int c = t; c < 768; c += 256) vm[c] = vmeanG[b * D_ + c];
  __syncthreads();
  int col = cc * 256 + t;
  float acc = 0;
#pragma unroll 4
  for (int k = 0; k < 768; ++k) acc += vm[k] * Wo[(size_t)k * D_ + col];
  outrowG[b * D_ + col] = acc;
}

// -------- fill masked rows of out with outrow[b] (fp32) --------
__global__ __launch_bounds__(256) void k_fillout(const int* __restrict__ xmask,
                                                 const float* __restrict__ outrowG,
                                                 float* __restrict__ out) {
  int b = blockIdx.y;
  int n = blockIdx.x * 32 + (threadIdx.x >> 3);
  int cg = threadIdx.x & 7;
  if (xmask[b * N_ + n]) return;
  const float* rp = outrowG + b * D_;
  float* op = out + ((size_t)b * N_ + n) * D_;
#pragma unroll
  for (int it = 0; it < 12; ++it) {
    int c = cg * 8 + it * 64;
    float4 v0 = *(const float4*)(rp + c);
    float4 v1 = *(const float4*)(rp + c + 4);
    *(float4*)(op + c) = v0;
    *(float4*)(op + c + 4) = v1;
  }
}

// -------- flash attention on compacted q/k (swapped-QK^T 32x32) --------
__global__ __launch_bounds__(256, 3) void k_attn(const short* __restrict__ Q,
                                                 const short* __restrict__ Kcg,
                                                 const short* __restrict__ Vtcg,
                                                 const int* __restrict__ cnt,
                                                 short* __restrict__ Aout) {
  int bh = blockIdx.y;
  int b = bh / H_, h = bh - b * H_;
  int cn = cnt[b];
  int nqt = (cn + 127) >> 7;
  if ((int)blockIdx.x >= nqt) return;  // block-uniform exit
  int nkt = (cn + 63) >> 6;
  const short* Qp = Q + (size_t)bh * N_ * DH_;
  const short* Kp = Kcg + (size_t)bh * N_ * DH_;
  const short* Vp = Vtcg + (size_t)bh * DH_ * N_;
  int q0 = blockIdx.x * 128;
  int tid = threadIdx.x, lane = tid & 63, w = tid >> 6;
  int lq = lane & 31, hi = lane >> 5;

  __shared__ char smem[32768];

  int qrow = q0 + 32 * w + lq;  // compacted q index (pad rows: Q=0, stores guarded)

  bf8_t qf[4];
#pragma unroll
  for (int kc = 0; kc < 4; ++kc)
    qf[kc] = *(const bf8_t*)(Qp + (size_t)qrow * DH_ + 16 * kc + 8 * hi);

  short NEGBIG = f2b(-1e30f);
  bf8_t qbf = {hi ? (short)0 : (short)0x3F80, 0, 0, 0, 0, 0, 0, 0};  // bias B (1.0)

  f16v acco[2];
#pragma unroll
  for (int i = 0; i < 16; ++i) { acco[0][i] = 0.f; acco[1][i] = 0.f; }
  float m = -1e29f, lsum = 0.f;

  auto STAGE = [&](int key0, int buf) {
    char* kb_ = smem + buf * 16384;
    char* vb_ = kb_ + 8192;
    int row = tid >> 3;
    int cb = (tid & 7) * 16;
    char* lk = kb_ + ((tid >> 6) << 10);
    char* lv = vb_ + ((tid >> 6) << 10);
#pragma unroll
    for (int rr = 0; rr < 2; ++rr) {
      int r2 = row + rr * 32;
      int sw = cb ^ ((r2 & 7) << 4);
      GLOAD_LDS16((const char*)(Kp + (size_t)(key0 + r2) * DH_) + sw, lk + rr * 4096);
      GLOAD_LDS16((const char*)(Vp + (size_t)r2 * N_ + key0) + sw, lv + rr * 4096);
    }
  };

  STAGE(0, 0);
  __syncthreads();

  for (int kt = 0; kt < nkt; ++kt) {
    int cur = kt & 1;
    if (kt + 1 < nkt) STAGE((kt + 1) * 64, cur ^ 1);

    const char* kbase = smem + cur * 16384;
    const char* vbase = kbase + 8192;
    int key0 = kt * 64;

    f16v accs[2];
#pragma unroll
    for (int i = 0; i < 16; ++i) { accs[0][i] = 0.f; accs[1][i] = 0.f; }
    int swz = (lq & 7) << 4;
    __builtin_amdgcn_s_setprio(1);
#pragma unroll
    for (int kc = 0; kc < 4; ++kc) {
      int colb = (32 * kc + 16 * hi) ^ swz;
      bf8_t k0 = *(const bf8_t*)(kbase + lq * 128 + colb);
      bf8_t k1 = *(const bf8_t*)(kbase + (32 + lq) * 128 + colb);
      accs[0] = __builtin_amdgcn_mfma_f32_32x32x16_bf16(k0, qf[kc], accs[0], 0, 0, 0);
      accs[1] = __builtin_amdgcn_mfma_f32_32x32x16_bf16(k1, qf[kc], accs[1], 0, 0, 0);
    }
    __builtin_amdgcn_s_setprio(0);
    if (key0 + 64 > cn) {  // tail guard: keys j >= cn get -1e30 bias
      bf8_t bf0 = {(hi || key0 + lq < cn) ? (short)0 : NEGBIG, 0, 0, 0, 0, 0, 0, 0};
      bf8_t bf1 = {(hi || key0 + 32 + lq < cn) ? (short)0 : NEGBIG, 0, 0, 0, 0, 0, 0, 0};
      accs[0] = __builtin_amdgcn_mfma_f32_32x32x16_bf16(bf0, qbf, accs[0], 0, 0, 0);
      accs[1] = __builtin_amdgcn_mfma_f32_32x32x16_bf16(bf1, qbf, accs[1], 0, 0, 0);
    }

    float mx = max3f(accs[0][0], accs[0][1], accs[0][2]);
#pragma unroll
    for (int i = 3; i < 15; i += 2) mx = max3f(mx, accs[0][i], accs[0][i + 1]);
    mx = max3f(mx, accs[0][15], accs[1][0]);
#pragma unroll
    for (int i = 1; i < 15; i += 2) mx = max3f(mx, accs[1][i], accs[1][i + 1]);
    mx = fmaxf(mx, accs[1][15]);
    mx = fmaxf(mx, __shfl_xor(mx, 32));
    if (!__all(mx <= m + 8.f)) {
      float mnew = fmaxf(m, mx);
      float sc = __builtin_amdgcn_exp2f(m - mnew);
      m = mnew;
      lsum *= sc;
#pragma unroll
      for (int i = 0; i < 16; ++i) { acco[0][i] *= sc; acco[1][i] *= sc; }
    }
    float psa[4] = {0.f, 0.f, 0.f, 0.f};
#pragma unroll
    for (int kb2 = 0; kb2 < 2; ++kb2)
#pragma unroll
      for (int r = 0; r < 16; ++r) {
        float p = __builtin_amdgcn_exp2f(accs[kb2][r] - m);
        accs[kb2][r] = p;
        psa[r & 3] += p;
      }
    float ps = (psa[0] + psa[1]) + (psa[2] + psa[3]);
    ps += __shfl_xor(ps, 32);
    lsum += ps;

    __builtin_amdgcn_s_setprio(1);
#pragma unroll
    for (int kc = 0; kc < 4; ++kc) {
      int kb2 = kc >> 1, rb = (kc & 1) * 8;
      unsigned a_ = cvtpk(accs[kb2][rb + 0], accs[kb2][rb + 1]);
      unsigned b_ = cvtpk(accs[kb2][rb + 4], accs[kb2][rb + 5]);
      unsigned c_ = cvtpk(accs[kb2][rb + 2], accs[kb2][rb + 3]);
      unsigned d_ = cvtpk(accs[kb2][rb + 6], accs[kb2][rb + 7]);
      plswap(a_, b_);
      plswap(c_, d_);
      union { i4_t i; bf8_t v; } pu;
      pu.i = (i4_t){(int)a_, (int)c_, (int)b_, (int)d_};
      int colb = (32 * kc + 16 * hi) ^ swz;
      bf8_t v0 = *(const bf8_t*)(vbase + lq * 128 + colb);
      bf8_t v1 = *(const bf8_t*)(vbase + (32 + lq) * 128 + colb);
      acco[0] = __builtin_amdgcn_mfma_f32_32x32x16_bf16(v0, pu.v, acco[0], 0, 0, 0);
      acco[1] = __builtin_amdgcn_mfma_f32_32x32x16_bf16(v1, pu.v, acco[1], 0, 0, 0);
    }
    __builtin_amdgcn_s_setprio(0);

    __syncthreads();
  }
  __syncthreads();  // all waves done with K/V buffers before Os reuse

  float inv = 1.f / lsum;
  unsigned* Os = (unsigned*)smem + w * 1152;
#pragma unroll
  for (int dhb = 0; dhb < 2; ++dhb)
#pragma unroll
    for (int r = 0; r < 16; r += 2) {
      unsigned pk = cvtpk(acco[dhb][r] * inv, acco[dhb][r + 1] * inv);
      int colu = 16 * dhb + ((r & 3) >> 1) + 4 * (r >> 2) + 2 * hi;
      Os[lq * 36 + colu] = pk;
    }
#pragma unroll
  for (int it = 0; it < 4; ++it) {
    int q = (lane >> 3) + 8 * it;
    int qr2 = q0 + 32 * w + q;
    if (qr2 < cn) {
      i4_t vv = *(const i4_t*)(Os + q * 36 + 4 * (lane & 7));
      union { i4_t i; bf8_t s; } u2;
      u2.i = vv;
      size_t off = ((size_t)b * N_ + qr2) * D_ + h * DH_ + 8 * (lane & 7);
      *(bf8_t*)(Aout + off) = u2.s;  // compacted row write
    }
  }
}

extern "C" void kernel_launch(void* const* d_in, const int* in_sizes, int n_in,
                              void* d_out, int out_size, void* d_ws, size_t ws_size,
                              hipStream_t stream) {
  (void)in_sizes; (void)n_in; (void)out_size; (void)ws_size;
  const float* x  = (const float*)d_in[0];
  const int*   xm = (const int*)d_in[1];
  const float* Wq = (const float*)d_in[2];
  const float* Wk = (const float*)d_in[3];
  const float* Wv = (const float*)d_in[4];
  const float* Wo = (const float*)d_in[5];
  float* out = (float*)d_out;
  char* ws = (char*)d_ws;

  short* xc      = (short*)(ws + 0);          // compacted bf16 x (12.6 MB)...
  short* Ao      = (short*)(ws + 0);          // ...reused as compacted attn out
  short* WqkvT   = (short*)(ws + 12582912);   // 3.5 MB
  short* WoT     = (short*)(ws + 16121856);   // 1.2 MB
  int*   idxb    = (int*)(ws + 17301504);     // 32 KB
  int*   cntb    = (int*)(ws + 17334272);     // 256 B
  float* xpart   = (float*)(ws + 17334528);   // 786 KB
  float* vmeanG  = (float*)(ws + 18120960);   // 12 KB
  float* outrowG = (float*)(ws + 18133248);   // 12 KB
  short* Qb      = (short*)(ws + 18874368);   // 12.6 MB (compacted)
  short* Kc      = (short*)(ws + 31457280);   // 12.6 MB (compacted)
  short* Vc      = (short*)(ws + 44040192);   // 12.6 MB (compacted)
  short* Vtc     = (short*)(ws + 56623104);   // 12.6 MB (ends 69.2 MB)

  k_maskidx<<<4, 256, 0, stream>>>(xm, idxb, cntb);
  k_xsumA<<<dim3(64, 4), 256, 0, stream>>>(x, xpart);
  k_gatherx<<<dim3(256, 4), 256, 0, stream>>>(x, idxb, cntb, xc);
  k_wtrans<<<dim3(12, 12, 4), 256, 0, stream>>>(Wq, Wk, Wv, Wo, WqkvT, WoT);
  k_gemm<0><<<dim3(18, 64), 256, 0, stream>>>(xc, WqkvT, 768, Qb, Kc, Vc,
                                              nullptr, 0, cntb, nullptr);
  k_vtrans<<<dim3(32, 48), 256, 0, stream>>>(Vc, cntb, Vtc);
  k_vmean<<<dim3(3, 4), 256, 0, stream>>>(xpart, Wv, vmeanG);
  k_outrow<<<dim3(3, 4), 256, 0, stream>>>(vmeanG, Wo, outrowG);
  k_attn<<<dim3(16, 48), 256, 0, stream>>>(Qb, Kc, Vtc, cntb, Ao);
  k_fillout<<<dim3(64, 4), 256, 0, stream>>>(xm, outrowG, out);
  k_gemm<1><<<dim3(6, 64), 256, 0, stream>>>(Ao, WoT, 768, nullptr, nullptr, nullptr,
                                             out, 768, cntb, idxb);
}

// Round 10
// 175.000 us; speedup vs baseline: 1.6149x; 1.6149x over previous
//
#include <hip/hip_runtime.h>

// Attention_73375221285454: fused MHA block on MI355X (gfx950)
// B=4 N=2048 D=768 H=12 DH=64. fp32 in/out, bf16 MFMA internally.
// Round 10: fix r9's latency-disaster GEMVs (k_vmean 79us, k_outrow ~65us:
// 12 blocks, 768-long serial chains). Now: k_xmean (split-chunk reduce) +
// k_gemv split-k (48 blocks, 64-wide coalesced, 192-fma chains, LDS reduce).
// Everything else identical to round 9 (compact-before-GEMM pipeline).

#define B_ 4
#define N_ 2048
#define D_ 768
#define H_ 12
#define DH_ 64
#define CSC_ 0.18033688011112042f  // SCALE * log2(e)

typedef __attribute__((ext_vector_type(8))) short bf8_t;   // 8 bf16 (MFMA A/B frag)
typedef __attribute__((ext_vector_type(4))) float f4_t;    // 16x16 C/D frag
typedef __attribute__((ext_vector_type(16))) float f16v;   // 32x32 C/D frag
typedef __attribute__((ext_vector_type(4))) int i4_t;

__device__ __forceinline__ short f2b(float f) {            // fp32 -> bf16 RNE
  union { float f; unsigned u; } v; v.f = f;
  unsigned r = v.u + 0x7FFFu + ((v.u >> 16) & 1u);
  return (short)(r >> 16);
}
__device__ __forceinline__ unsigned cvtpk(float lo, float hi) {
  unsigned r;
  asm("v_cvt_pk_bf16_f32 %0, %1, %2" : "=v"(r) : "v"(lo), "v"(hi));
  return r;
}
__device__ __forceinline__ void plswap(unsigned& a, unsigned& b) {
  asm("v_permlane32_swap_b32 %0, %1" : "+v"(a), "+v"(b));
}
__device__ __forceinline__ float max3f(float a, float b, float c) {
  float r;
  asm("v_max3_f32 %0, %1, %2, %3" : "=v"(r) : "v"(a), "v"(b), "v"(c));
  return r;
}

#define GLOAD_LDS16(gp, lp)                                                       \
  __builtin_amdgcn_global_load_lds(                                               \
      (const __attribute__((address_space(1))) void*)(gp),                        \
      (__attribute__((address_space(3))) void*)(lp), 16, 0, 0)

// ---------------- per-batch valid-index list (order-preserving scan) ----------------
__global__ __launch_bounds__(256) void k_maskidx(const int* __restrict__ xmask,
                                                 int* __restrict__ idx,
                                                 int* __restrict__ cnt) {
  int b = blockIdx.x, t = threadIdx.x;
  const int* mp = xmask + b * N_;
  int loc[8], c = 0;
#pragma unroll
  for (int j = 0; j < 8; ++j) {
    int n = t * 8 + j;
    if (mp[n]) loc[c++] = n;
  }
  __shared__ int sc[256];
  sc[t] = c;
  __syncthreads();
  for (int off = 1; off < 256; off <<= 1) {
    int v = (t >= off) ? sc[t - off] : 0;
    __syncthreads();
    sc[t] += v;
    __syncthreads();
  }
  int base = sc[t] - c;
  int* op = idx + b * N_;
  for (int j = 0; j < c; ++j) op[base + j] = loc[j];
  if (t == 255) cnt[b] = sc[255];
}

// ------- xsum stage A: per-(b,chunk-of-32-rows) column sums of x (fp32) -------
__global__ __launch_bounds__(256) void k_xsumA(const float* __restrict__ x,
                                               float* __restrict__ xpart) {
  int b = blockIdx.y, ch = blockIdx.x, t = threadIdx.x;
  const float* xp = x + ((size_t)b * N_ + ch * 32) * D_;
  float a0 = 0, a1 = 0, a2 = 0;
  for (int r = 0; r < 32; ++r) {
    const float* rp = xp + (size_t)r * D_;
    a0 += rp[t]; a1 += rp[t + 256]; a2 += rp[t + 512];
  }
  float* op = xpart + ((size_t)b * 64 + ch) * D_;
  op[t] = a0; op[t + 256] = a1; op[t + 512] = a2;
}

// ------- xmean[b][c] = (1/2048) sum_ch xpart[b][ch][c]  (48 blocks, coalesced) -------
__global__ __launch_bounds__(256) void k_xmean(const float* __restrict__ xpart,
                                               float* __restrict__ xmean) {
  int b = blockIdx.y;
  int col = blockIdx.x * 64 + (threadIdx.x & 63);
  int grp = threadIdx.x >> 6;
  float s = 0;
#pragma unroll
  for (int i = 0; i < 16; ++i)
    s += xpart[((size_t)b * 64 + grp * 16 + i) * D_ + col];
  __shared__ float red[4][64];
  red[grp][threadIdx.x & 63] = s;
  __syncthreads();
  if (grp == 0) {
    int cl = threadIdx.x & 63;
    xmean[b * D_ + col] = (red[0][cl] + red[1][cl] + red[2][cl] + red[3][cl]) * (1.f / 2048.f);
  }
}

// ------- y[b][col] = sum_k xv[b][k] * W[k][col]  (split-k GEMV, 48 blocks) -------
__global__ __launch_bounds__(256) void k_gemv(const float* __restrict__ xv,
                                              const float* __restrict__ W,
                                              float* __restrict__ y) {
  int b = blockIdx.y;
  int cl = threadIdx.x & 63;
  int col = blockIdx.x * 64 + cl;
  int grp = threadIdx.x >> 6;
  __shared__ float xs[768];
  for (int c = threadIdx.x; c < 768; c += 256) xs[c] = xv[b * D_ + c];
  __syncthreads();
  float acc = 0;
  const float* wp = W + (size_t)(grp * 192) * D_ + col;
  const float* xp = xs + grp * 192;
#pragma unroll 4
  for (int k = 0; k < 192; ++k) acc += xp[k] * wp[(size_t)k * D_];
  __shared__ float red[4][64];
  red[grp][cl] = acc;
  __syncthreads();
  if (grp == 0) y[b * D_ + col] = red[0][cl] + red[1][cl] + red[2][cl] + red[3][cl];
}

// ------- gather valid x rows -> compacted bf16 xc (zero rows beyond cnt) -------
__global__ __launch_bounds__(256) void k_gatherx(const float* __restrict__ x,
                                                 const int* __restrict__ idx,
                                                 const int* __restrict__ cnt,
                                                 short* __restrict__ xc) {
  int b = blockIdx.y;
  int j = blockIdx.x * 8 + (threadIdx.x >> 5);
  int cn = cnt[b];
  int l5 = threadIdx.x & 31;
  short* op = xc + ((size_t)b * N_ + j) * D_;
  if (j < cn) {
    int n = idx[b * N_ + j];
    const float* rp = x + ((size_t)b * N_ + n) * D_;
#pragma unroll
    for (int it = 0; it < 3; ++it) {
      int c = (l5 + it * 32) * 8;
      float4 v0 = *(const float4*)(rp + c);
      float4 v1 = *(const float4*)(rp + c + 4);
      bf8_t o;
      o[0] = f2b(v0.x); o[1] = f2b(v0.y); o[2] = f2b(v0.z); o[3] = f2b(v0.w);
      o[4] = f2b(v1.x); o[5] = f2b(v1.y); o[6] = f2b(v1.z); o[7] = f2b(v1.w);
      *(bf8_t*)(op + c) = o;
    }
  } else {
    const bf8_t zz = {0, 0, 0, 0, 0, 0, 0, 0};
#pragma unroll
    for (int it = 0; it < 3; ++it) {
      int c = (l5 + it * 32) * 8;
      *(bf8_t*)(op + c) = zz;
    }
  }
}

// ------- prep: transpose weights fp32->bf16 into B^T layout; Wq pre-scaled -------
__global__ __launch_bounds__(256) void k_wtrans(const float* __restrict__ Wq,
                                                const float* __restrict__ Wk,
                                                const float* __restrict__ Wv,
                                                const float* __restrict__ Wo,
                                                short* __restrict__ WqkvT,
                                                short* __restrict__ WoT) {
  int z = blockIdx.z;
  const float* W = (z == 0) ? Wq : (z == 1) ? Wk : (z == 2) ? Wv : Wo;
  short* dst = (z < 3) ? (WqkvT + (size_t)z * D_ * D_) : WoT;
  float sc = (z == 0) ? CSC_ : 1.f;
  __shared__ float T[64][65];
  int r0 = blockIdx.y * 64, c0 = blockIdx.x * 64;
  int tr = threadIdx.x >> 6, tc = threadIdx.x & 63;
#pragma unroll
  for (int i = 0; i < 16; ++i) {
    int r = tr + i * 4;
    T[r][tc] = W[(size_t)(r0 + r) * D_ + c0 + tc];
  }
  __syncthreads();
#pragma unroll
  for (int i = 0; i < 16; ++i) {
    int r = tr + i * 4;
    dst[(size_t)(c0 + r) * D_ + r0 + tc] = f2b(T[tc][r] * sc);
  }
}

// ------- GEMM (r8 structure + compaction exit): C = A[M x K] * BT[Ncol x K]^T -------
template <int MODE>
__global__ __launch_bounds__(256) void k_gemm(const short* __restrict__ A,
                                              const short* __restrict__ BT, int K,
                                              short* __restrict__ Qb, short* __restrict__ Kb,
                                              short* __restrict__ Vb,
                                              float* __restrict__ Cout, int ldc,
                                              const int* __restrict__ cnt,
                                              const int* __restrict__ idx) {
  __shared__ short As[2][128 * 64];
  __shared__ short Bs[2][128 * 64];
  int gx = gridDim.x;
  int nwg = gx * gridDim.y;
  int flat = blockIdx.y * gx + blockIdx.x;
  int cpx = nwg >> 3;
  int swzb = (flat & 7) * cpx + (flat >> 3);
  int row0 = (swzb / gx) * 128, col0 = (swzb % gx) * 128;

  int bb = row0 >> 11;
  int cn = cnt[bb];
  int cnpad = (cn + 127) & ~127;
  if ((row0 & 2047) >= cnpad) return;  // masked-row tile: nothing to do

  int tid = threadIdx.x, lane = tid & 63, w = tid >> 6;
  int wr = w >> 1, wc = w & 1;
  int lr = lane & 15, lhi = lane >> 4;
  f4_t acc[4][4];
#pragma unroll
  for (int mi = 0; mi < 4; ++mi)
#pragma unroll
    for (int ni = 0; ni < 4; ++ni) acc[mi][ni] = (f4_t){0.f, 0.f, 0.f, 0.f};

  int sub = lane >> 3;
  int scb = ((lane & 7) * 16) ^ (sub << 4);
  auto STAGE = [&](int k0, int buf) {
    char* ab = (char*)As[buf] + (w << 12);
    char* bb2 = (char*)Bs[buf] + (w << 12);
#pragma unroll
    for (int i = 0; i < 4; ++i) {
      int r = 32 * w + 8 * i + sub;
      GLOAD_LDS16((const char*)(A + (size_t)(row0 + r) * K + k0) + scb, ab + (i << 10));
      GLOAD_LDS16((const char*)(BT + (size_t)(col0 + r) * K + k0) + scb, bb2 + (i << 10));
    }
  };

  STAGE(0, 0);

  int nt = K / 64;
  for (int t = 0; t < nt; ++t) {
    int cur = t & 1;
    if (t + 1 < nt) {
      STAGE((t + 1) * 64, cur ^ 1);
      asm volatile("s_waitcnt vmcnt(8)" ::: "memory");
    } else {
      asm volatile("s_waitcnt vmcnt(0)" ::: "memory");
    }
    __builtin_amdgcn_sched_barrier(0);
    __builtin_amdgcn_s_barrier();

    const char* Ac = (const char*)As[cur];
    const char* Bc = (const char*)Bs[cur];
    int rsw = (lr & 7) << 4;
#pragma unroll
    for (int kc = 0; kc < 2; ++kc) {
      bf8_t av[4], bv[4];
#pragma unroll
      for (int mi = 0; mi < 4; ++mi) {
        int row = 64 * wr + 16 * mi + lr;
        av[mi] = *(const bf8_t*)(Ac + row * 128 + ((64 * kc + 16 * lhi) ^ rsw));
      }
#pragma unroll
      for (int ni = 0; ni < 4; ++ni) {
        int row = 64 * wc + 16 * ni + lr;
        bv[ni] = *(const bf8_t*)(Bc + row * 128 + ((64 * kc + 16 * lhi) ^ rsw));
      }
#pragma unroll
      for (int mi = 0; mi < 4; ++mi)
#pragma unroll
        for (int ni = 0; ni < 4; ++ni)
          acc[mi][ni] = __builtin_amdgcn_mfma_f32_16x16x32_bf16(av[mi], bv[ni], acc[mi][ni], 0, 0, 0);
    }
    __builtin_amdgcn_sched_barrier(0);
    __builtin_amdgcn_s_barrier();
  }

#pragma unroll
  for (int mi = 0; mi < 4; ++mi)
#pragma unroll
    for (int ni = 0; ni < 4; ++ni)
#pragma unroll
      for (int r = 0; r < 4; ++r) {
        int row = row0 + 64 * wr + 16 * mi + 4 * lhi + r;
        int col = col0 + 64 * wc + 16 * ni + lr;
        float v = acc[mi][ni][r];
        if (MODE == 0) {
          int which = col / 768;
          int cc2 = col - which * 768;
          int h = cc2 >> 6, dh = cc2 & 63;
          int b = row >> 11, n = row & 2047;  // compacted index
          size_t dst = (((size_t)(b * H_ + h)) * N_ + n) * DH_ + dh;
          short bv2 = f2b(v);
          if (which == 0) Qb[dst] = bv2;
          else if (which == 1) Kb[dst] = bv2;
          else Vb[dst] = bv2;
        } else {
          int j = row & 2047;
          if (j < cn) {
            int n = idx[(row & ~2047) + j];
            Cout[((size_t)(row & ~2047) + n) * ldc + col] = v;
          }
        }
      }
}

// ---------------- Vc[bh][j][dh] -> Vtc[bh][dh][j] (compacted) ----------------
__global__ __launch_bounds__(256) void k_vtrans(const short* __restrict__ V,
                                                const int* __restrict__ cnt,
                                                short* __restrict__ Vt) {
  int bh = blockIdx.y, b = bh / H_;
  int n0 = blockIdx.x * 64;
  int cn = cnt[b];
  int cnpad = (cn + 127) & ~127;
  if (n0 >= cnpad) return;
  __shared__ short T[64][72];
  int tr = threadIdx.x >> 6, tc = threadIdx.x & 63;
  const short* Vp = V + (size_t)bh * N_ * DH_;
  short* Vtp = Vt + (size_t)bh * DH_ * N_;
#pragma unroll
  for (int i = 0; i < 16; ++i) {
    int r = tr + i * 4;
    T[r][tc] = Vp[(size_t)(n0 + r) * DH_ + tc];
  }
  __syncthreads();
#pragma unroll
  for (int i = 0; i < 16; ++i) {
    int r = tr + i * 4;
    Vtp[(size_t)r * N_ + n0 + tc] = T[tc][r];
  }
}

// -------- fill masked rows of out with outrow[b] (fp32) --------
__global__ __launch_bounds__(256) void k_fillout(const int* __restrict__ xmask,
                                                 const float* __restrict__ outrowG,
                                                 float* __restrict__ out) {
  int b = blockIdx.y;
  int n = blockIdx.x * 32 + (threadIdx.x >> 3);
  int cg = threadIdx.x & 7;
  if (xmask[b * N_ + n]) return;
  const float* rp = outrowG + b * D_;
  float* op = out + ((size_t)b * N_ + n) * D_;
#pragma unroll
  for (int it = 0; it < 12; ++it) {
    int c = cg * 8 + it * 64;
    float4 v0 = *(const float4*)(rp + c);
    float4 v1 = *(const float4*)(rp + c + 4);
    *(float4*)(op + c) = v0;
    *(float4*)(op + c + 4) = v1;
  }
}

// -------- flash attention on compacted q/k (swapped-QK^T 32x32) --------
__global__ __launch_bounds__(256, 3) void k_attn(const short* __restrict__ Q,
                                                 const short* __restrict__ Kcg,
                                                 const short* __restrict__ Vtcg,
                                                 const int* __restrict__ cnt,
                                                 short* __restrict__ Aout) {
  int bh = blockIdx.y;
  int b = bh / H_, h = bh - b * H_;
  int cn = cnt[b];
  int nqt = (cn + 127) >> 7;
  if ((int)blockIdx.x >= nqt) return;
  int nkt = (cn + 63) >> 6;
  const short* Qp = Q + (size_t)bh * N_ * DH_;
  const short* Kp = Kcg + (size_t)bh * N_ * DH_;
  const short* Vp = Vtcg + (size_t)bh * DH_ * N_;
  int q0 = blockIdx.x * 128;
  int tid = threadIdx.x, lane = tid & 63, w = tid >> 6;
  int lq = lane & 31, hi = lane >> 5;

  __shared__ char smem[32768];

  int qrow = q0 + 32 * w + lq;

  bf8_t qf[4];
#pragma unroll
  for (int kc = 0; kc < 4; ++kc)
    qf[kc] = *(const bf8_t*)(Qp + (size_t)qrow * DH_ + 16 * kc + 8 * hi);

  short NEGBIG = f2b(-1e30f);
  bf8_t qbf = {hi ? (short)0 : (short)0x3F80, 0, 0, 0, 0, 0, 0, 0};

  f16v acco[2];
#pragma unroll
  for (int i = 0; i < 16; ++i) { acco[0][i] = 0.f; acco[1][i] = 0.f; }
  float m = -1e29f, lsum = 0.f;

  auto STAGE = [&](int key0, int buf) {
    char* kb_ = smem + buf * 16384;
    char* vb_ = kb_ + 8192;
    int row = tid >> 3;
    int cb = (tid & 7) * 16;
    char* lk = kb_ + ((tid >> 6) << 10);
    char* lv = vb_ + ((tid >> 6) << 10);
#pragma unroll
    for (int rr = 0; rr < 2; ++rr) {
      int r2 = row + rr * 32;
      int sw = cb ^ ((r2 & 7) << 4);
      GLOAD_LDS16((const char*)(Kp + (size_t)(key0 + r2) * DH_) + sw, lk + rr * 4096);
      GLOAD_LDS16((const char*)(Vp + (size_t)r2 * N_ + key0) + sw, lv + rr * 4096);
    }
  };

  STAGE(0, 0);
  __syncthreads();

  for (int kt = 0; kt < nkt; ++kt) {
    int cur = kt & 1;
    if (kt + 1 < nkt) STAGE((kt + 1) * 64, cur ^ 1);

    const char* kbase = smem + cur * 16384;
    const char* vbase = kbase + 8192;
    int key0 = kt * 64;

    f16v accs[2];
#pragma unroll
    for (int i = 0; i < 16; ++i) { accs[0][i] = 0.f; accs[1][i] = 0.f; }
    int swz = (lq & 7) << 4;
    __builtin_amdgcn_s_setprio(1);
#pragma unroll
    for (int kc = 0; kc < 4; ++kc) {
      int colb = (32 * kc + 16 * hi) ^ swz;
      bf8_t k0 = *(const bf8_t*)(kbase + lq * 128 + colb);
      bf8_t k1 = *(const bf8_t*)(kbase + (32 + lq) * 128 + colb);
      accs[0] = __builtin_amdgcn_mfma_f32_32x32x16_bf16(k0, qf[kc], accs[0], 0, 0, 0);
      accs[1] = __builtin_amdgcn_mfma_f32_32x32x16_bf16(k1, qf[kc], accs[1], 0, 0, 0);
    }
    __builtin_amdgcn_s_setprio(0);
    if (key0 + 64 > cn) {
      bf8_t bf0 = {(hi || key0 + lq < cn) ? (short)0 : NEGBIG, 0, 0, 0, 0, 0, 0, 0};
      bf8_t bf1 = {(hi || key0 + 32 + lq < cn) ? (short)0 : NEGBIG, 0, 0, 0, 0, 0, 0, 0};
      accs[0] = __builtin_amdgcn_mfma_f32_32x32x16_bf16(bf0, qbf, accs[0], 0, 0, 0);
      accs[1] = __builtin_amdgcn_mfma_f32_32x32x16_bf16(bf1, qbf, accs[1], 0, 0, 0);
    }

    float mx = max3f(accs[0][0], accs[0][1], accs[0][2]);
#pragma unroll
    for (int i = 3; i < 15; i += 2) mx = max3f(mx, accs[0][i], accs[0][i + 1]);
    mx = max3f(mx, accs[0][15], accs[1][0]);
#pragma unroll
    for (int i = 1; i < 15; i += 2) mx = max3f(mx, accs[1][i], accs[1][i + 1]);
    mx = fmaxf(mx, accs[1][15]);
    mx = fmaxf(mx, __shfl_xor(mx, 32));
    if (!__all(mx <= m + 8.f)) {
      float mnew = fmaxf(m, mx);
      float sc = __builtin_amdgcn_exp2f(m - mnew);
      m = mnew;
      lsum *= sc;
#pragma unroll
      for (int i = 0; i < 16; ++i) { acco[0][i] *= sc; acco[1][i] *= sc; }
    }
    float psa[4] = {0.f, 0.f, 0.f, 0.f};
#pragma unroll
    for (int kb2 = 0; kb2 < 2; ++kb2)
#pragma unroll
      for (int r = 0; r < 16; ++r) {
        float p = __builtin_amdgcn_exp2f(accs[kb2][r] - m);
        accs[kb2][r] = p;
        psa[r & 3] += p;
      }
    float ps = (psa[0] + psa[1]) + (psa[2] + psa[3]);
    ps += __shfl_xor(ps, 32);
    lsum += ps;

    __builtin_amdgcn_s_setprio(1);
#pragma unroll
    for (int kc = 0; kc < 4; ++kc) {
      int kb2 = kc >> 1, rb = (kc & 1) * 8;
      unsigned a_ = cvtpk(accs[kb2][rb + 0], accs[kb2][rb + 1]);
      unsigned b_ = cvtpk(accs[kb2][rb + 4], accs[kb2][rb + 5]);
      unsigned c_ = cvtpk(accs[kb2][rb + 2], accs[kb2][rb + 3]);
      unsigned d_ = cvtpk(accs[kb2][rb + 6], accs[kb2][rb + 7]);
      plswap(a_, b_);
      plswap(c_, d_);
      union { i4_t i; bf8_t v; } pu;
      pu.i = (i4_t){(int)a_, (int)c_, (int)b_, (int)d_};
      int colb = (32 * kc + 16 * hi) ^ swz;
      bf8_t v0 = *(const bf8_t*)(vbase + lq * 128 + colb);
      bf8_t v1 = *(const bf8_t*)(vbase + (32 + lq) * 128 + colb);
      acco[0] = __builtin_amdgcn_mfma_f32_32x32x16_bf16(v0, pu.v, acco[0], 0, 0, 0);
      acco[1] = __builtin_amdgcn_mfma_f32_32x32x16_bf16(v1, pu.v, acco[1], 0, 0, 0);
    }
    __builtin_amdgcn_s_setprio(0);

    __syncthreads();
  }
  __syncthreads();

  float inv = 1.f / lsum;
  unsigned* Os = (unsigned*)smem + w * 1152;
#pragma unroll
  for (int dhb = 0; dhb < 2; ++dhb)
#pragma unroll
    for (int r = 0; r < 16; r += 2) {
      unsigned pk = cvtpk(acco[dhb][r] * inv, acco[dhb][r + 1] * inv);
      int colu = 16 * dhb + ((r & 3) >> 1) + 4 * (r >> 2) + 2 * hi;
      Os[lq * 36 + colu] = pk;
    }
#pragma unroll
  for (int it = 0; it < 4; ++it) {
    int q = (lane >> 3) + 8 * it;
    int qr2 = q0 + 32 * w + q;
    if (qr2 < cn) {
      i4_t vv = *(const i4_t*)(Os + q * 36 + 4 * (lane & 7));
      union { i4_t i; bf8_t s; } u2;
      u2.i = vv;
      size_t off = ((size_t)b * N_ + qr2) * D_ + h * DH_ + 8 * (lane & 7);
      *(bf8_t*)(Aout + off) = u2.s;
    }
  }
}

extern "C" void kernel_launch(void* const* d_in, const int* in_sizes, int n_in,
                              void* d_out, int out_size, void* d_ws, size_t ws_size,
                              hipStream_t stream) {
  (void)in_sizes; (void)n_in; (void)out_size; (void)ws_size;
  const float* x  = (const float*)d_in[0];
  const int*   xm = (const int*)d_in[1];
  const float* Wq = (const float*)d_in[2];
  const float* Wk = (const float*)d_in[3];
  const float* Wv = (const float*)d_in[4];
  const float* Wo = (const float*)d_in[5];
  float* out = (float*)d_out;
  char* ws = (char*)d_ws;

  short* xc      = (short*)(ws + 0);          // compacted bf16 x ...
  short* Ao      = (short*)(ws + 0);          // ...reused as compacted attn out
  short* WqkvT   = (short*)(ws + 12582912);
  short* WoT     = (short*)(ws + 16121856);
  int*   idxb    = (int*)(ws + 17301504);
  int*   cntb    = (int*)(ws + 17334272);
  float* xpart   = (float*)(ws + 17334528);
  float* vmeanG  = (float*)(ws + 18120960);
  float* outrowG = (float*)(ws + 18133248);
  float* xmeanG  = (float*)(ws + 18145536);
  short* Qb      = (short*)(ws + 18874368);
  short* Kc      = (short*)(ws + 31457280);
  short* Vc      = (short*)(ws + 44040192);
  short* Vtc     = (short*)(ws + 56623104);

  k_maskidx<<<4, 256, 0, stream>>>(xm, idxb, cntb);
  k_xsumA<<<dim3(64, 4), 256, 0, stream>>>(x, xpart);
  k_gatherx<<<dim3(256, 4), 256, 0, stream>>>(x, idxb, cntb, xc);
  k_wtrans<<<dim3(12, 12, 4), 256, 0, stream>>>(Wq, Wk, Wv, Wo, WqkvT, WoT);
  k_gemm<0><<<dim3(18, 64), 256, 0, stream>>>(xc, WqkvT, 768, Qb, Kc, Vc,
                                              nullptr, 0, cntb, nullptr);
  k_vtrans<<<dim3(32, 48), 256, 0, stream>>>(Vc, cntb, Vtc);
  k_xmean<<<dim3(12, 4), 256, 0, stream>>>(xpart, xmeanG);
  k_gemv<<<dim3(12, 4), 256, 0, stream>>>(xmeanG, Wv, vmeanG);
  k_gemv<<<dim3(12, 4), 256, 0, stream>>>(vmeanG, Wo, outrowG);
  k_attn<<<dim3(16, 48), 256, 0, stream>>>(Qb, Kc, Vtc, cntb, Ao);
  k_fillout<<<dim3(64, 4), 256, 0, stream>>>(xm, outrowG, out);
  k_gemm<1><<<dim3(6, 64), 256, 0, stream>>>(Ao, WoT, 768, nullptr, nullptr, nullptr,
                                             out, 768, cntb, idxb);
}

// Round 11
// 163.196 us; speedup vs baseline: 1.7317x; 1.0723x over previous
//
#include <hip/hip_runtime.h>

// Attention_73375221285454: fused MHA block on MI355X (gfx950)
// B=4 N=2048 D=768 H=12 DH=64. fp32 in/out, bf16 MFMA internally.
// Round 11: ONE change vs r10 — XCD swizzle axis flipped in k_gemm.
// r10's row-slow mapping gave each XCD a contiguous row-tile range, so the
// compaction early-exit idled 4 of 8 XCDs (dur unchanged at half work,
// MfmaUtil halved). Now row_tile = swzb % gridDim.y (fast axis): every XCD
// sees all row tiles (balanced exits) and shares ~2 B-column panels (L2).

#define B_ 4
#define N_ 2048
#define D_ 768
#define H_ 12
#define DH_ 64
#define CSC_ 0.18033688011112042f  // SCALE * log2(e)

typedef __attribute__((ext_vector_type(8))) short bf8_t;   // 8 bf16 (MFMA A/B frag)
typedef __attribute__((ext_vector_type(4))) float f4_t;    // 16x16 C/D frag
typedef __attribute__((ext_vector_type(16))) float f16v;   // 32x32 C/D frag
typedef __attribute__((ext_vector_type(4))) int i4_t;

__device__ __forceinline__ short f2b(float f) {            // fp32 -> bf16 RNE
  union { float f; unsigned u; } v; v.f = f;
  unsigned r = v.u + 0x7FFFu + ((v.u >> 16) & 1u);
  return (short)(r >> 16);
}
__device__ __forceinline__ unsigned cvtpk(float lo, float hi) {
  unsigned r;
  asm("v_cvt_pk_bf16_f32 %0, %1, %2" : "=v"(r) : "v"(lo), "v"(hi));
  return r;
}
__device__ __forceinline__ void plswap(unsigned& a, unsigned& b) {
  asm("v_permlane32_swap_b32 %0, %1" : "+v"(a), "+v"(b));
}
__device__ __forceinline__ float max3f(float a, float b, float c) {
  float r;
  asm("v_max3_f32 %0, %1, %2, %3" : "=v"(r) : "v"(a), "v"(b), "v"(c));
  return r;
}

#define GLOAD_LDS16(gp, lp)                                                       \
  __builtin_amdgcn_global_load_lds(                                               \
      (const __attribute__((address_space(1))) void*)(gp),                        \
      (__attribute__((address_space(3))) void*)(lp), 16, 0, 0)

// ---------------- per-batch valid-index list (order-preserving scan) ----------------
__global__ __launch_bounds__(256) void k_maskidx(const int* __restrict__ xmask,
                                                 int* __restrict__ idx,
                                                 int* __restrict__ cnt) {
  int b = blockIdx.x, t = threadIdx.x;
  const int* mp = xmask + b * N_;
  int loc[8], c = 0;
#pragma unroll
  for (int j = 0; j < 8; ++j) {
    int n = t * 8 + j;
    if (mp[n]) loc[c++] = n;
  }
  __shared__ int sc[256];
  sc[t] = c;
  __syncthreads();
  for (int off = 1; off < 256; off <<= 1) {
    int v = (t >= off) ? sc[t - off] : 0;
    __syncthreads();
    sc[t] += v;
    __syncthreads();
  }
  int base = sc[t] - c;
  int* op = idx + b * N_;
  for (int j = 0; j < c; ++j) op[base + j] = loc[j];
  if (t == 255) cnt[b] = sc[255];
}

// ------- xsum stage A: per-(b,chunk-of-32-rows) column sums of x (fp32) -------
__global__ __launch_bounds__(256) void k_xsumA(const float* __restrict__ x,
                                               float* __restrict__ xpart) {
  int b = blockIdx.y, ch = blockIdx.x, t = threadIdx.x;
  const float* xp = x + ((size_t)b * N_ + ch * 32) * D_;
  float a0 = 0, a1 = 0, a2 = 0;
  for (int r = 0; r < 32; ++r) {
    const float* rp = xp + (size_t)r * D_;
    a0 += rp[t]; a1 += rp[t + 256]; a2 += rp[t + 512];
  }
  float* op = xpart + ((size_t)b * 64 + ch) * D_;
  op[t] = a0; op[t + 256] = a1; op[t + 512] = a2;
}

// ------- xmean[b][c] = (1/2048) sum_ch xpart[b][ch][c] -------
__global__ __launch_bounds__(256) void k_xmean(const float* __restrict__ xpart,
                                               float* __restrict__ xmean) {
  int b = blockIdx.y;
  int col = blockIdx.x * 64 + (threadIdx.x & 63);
  int grp = threadIdx.x >> 6;
  float s = 0;
#pragma unroll
  for (int i = 0; i < 16; ++i)
    s += xpart[((size_t)b * 64 + grp * 16 + i) * D_ + col];
  __shared__ float red[4][64];
  red[grp][threadIdx.x & 63] = s;
  __syncthreads();
  if (grp == 0) {
    int cl = threadIdx.x & 63;
    xmean[b * D_ + col] = (red[0][cl] + red[1][cl] + red[2][cl] + red[3][cl]) * (1.f / 2048.f);
  }
}

// ------- y[b][col] = sum_k xv[b][k] * W[k][col]  (split-k GEMV) -------
__global__ __launch_bounds__(256) void k_gemv(const float* __restrict__ xv,
                                              const float* __restrict__ W,
                                              float* __restrict__ y) {
  int b = blockIdx.y;
  int cl = threadIdx.x & 63;
  int col = blockIdx.x * 64 + cl;
  int grp = threadIdx.x >> 6;
  __shared__ float xs[768];
  for (int c = threadIdx.x; c < 768; c += 256) xs[c] = xv[b * D_ + c];
  __syncthreads();
  float acc = 0;
  const float* wp = W + (size_t)(grp * 192) * D_ + col;
  const float* xp = xs + grp * 192;
#pragma unroll 4
  for (int k = 0; k < 192; ++k) acc += xp[k] * wp[(size_t)k * D_];
  __shared__ float red[4][64];
  red[grp][cl] = acc;
  __syncthreads();
  if (grp == 0) y[b * D_ + col] = red[0][cl] + red[1][cl] + red[2][cl] + red[3][cl];
}

// ------- gather valid x rows -> compacted bf16 xc (zero rows beyond cnt) -------
__global__ __launch_bounds__(256) void k_gatherx(const float* __restrict__ x,
                                                 const int* __restrict__ idx,
                                                 const int* __restrict__ cnt,
                                                 short* __restrict__ xc) {
  int b = blockIdx.y;
  int j = blockIdx.x * 8 + (threadIdx.x >> 5);
  int cn = cnt[b];
  int l5 = threadIdx.x & 31;
  short* op = xc + ((size_t)b * N_ + j) * D_;
  if (j < cn) {
    int n = idx[b * N_ + j];
    const float* rp = x + ((size_t)b * N_ + n) * D_;
#pragma unroll
    for (int it = 0; it < 3; ++it) {
      int c = (l5 + it * 32) * 8;
      float4 v0 = *(const float4*)(rp + c);
      float4 v1 = *(const float4*)(rp + c + 4);
      bf8_t o;
      o[0] = f2b(v0.x); o[1] = f2b(v0.y); o[2] = f2b(v0.z); o[3] = f2b(v0.w);
      o[4] = f2b(v1.x); o[5] = f2b(v1.y); o[6] = f2b(v1.z); o[7] = f2b(v1.w);
      *(bf8_t*)(op + c) = o;
    }
  } else {
    const bf8_t zz = {0, 0, 0, 0, 0, 0, 0, 0};
#pragma unroll
    for (int it = 0; it < 3; ++it) {
      int c = (l5 + it * 32) * 8;
      *(bf8_t*)(op + c) = zz;
    }
  }
}

// ------- prep: transpose weights fp32->bf16 into B^T layout; Wq pre-scaled -------
__global__ __launch_bounds__(256) void k_wtrans(const float* __restrict__ Wq,
                                                const float* __restrict__ Wk,
                                                const float* __restrict__ Wv,
                                                const float* __restrict__ Wo,
                                                short* __restrict__ WqkvT,
                                                short* __restrict__ WoT) {
  int z = blockIdx.z;
  const float* W = (z == 0) ? Wq : (z == 1) ? Wk : (z == 2) ? Wv : Wo;
  short* dst = (z < 3) ? (WqkvT + (size_t)z * D_ * D_) : WoT;
  float sc = (z == 0) ? CSC_ : 1.f;
  __shared__ float T[64][65];
  int r0 = blockIdx.y * 64, c0 = blockIdx.x * 64;
  int tr = threadIdx.x >> 6, tc = threadIdx.x & 63;
#pragma unroll
  for (int i = 0; i < 16; ++i) {
    int r = tr + i * 4;
    T[r][tc] = W[(size_t)(r0 + r) * D_ + c0 + tc];
  }
  __syncthreads();
#pragma unroll
  for (int i = 0; i < 16; ++i) {
    int r = tr + i * 4;
    dst[(size_t)(c0 + r) * D_ + r0 + tc] = f2b(T[tc][r] * sc);
  }
}

// ------- GEMM (r8 structure + compaction exit + balanced XCD swizzle) -------
// row_tile = swzb % gridDim.y (FAST axis): each XCD's contiguous swzb chunk
// cycles all row tiles -> compaction exits spread evenly across XCDs; blocks
// within an XCD share B-column panels (L2 reuse).
template <int MODE>
__global__ __launch_bounds__(256) void k_gemm(const short* __restrict__ A,
                                              const short* __restrict__ BT, int K,
                                              short* __restrict__ Qb, short* __restrict__ Kb,
                                              short* __restrict__ Vb,
                                              float* __restrict__ Cout, int ldc,
                                              const int* __restrict__ cnt,
                                              const int* __restrict__ idx) {
  __shared__ short As[2][128 * 64];
  __shared__ short Bs[2][128 * 64];
  int gx = gridDim.x, gy = gridDim.y;
  int nwg = gx * gy;
  int flat = blockIdx.y * gx + blockIdx.x;
  int cpx = nwg >> 3;
  int swzb = (flat & 7) * cpx + (flat >> 3);
  int row0 = (swzb % gy) * 128, col0 = (swzb / gy) * 128;  // row FAST axis

  int bb = row0 >> 11;
  int cn = cnt[bb];
  int cnpad = (cn + 127) & ~127;
  if ((row0 & 2047) >= cnpad) return;  // masked-row tile: nothing to do

  int tid = threadIdx.x, lane = tid & 63, w = tid >> 6;
  int wr = w >> 1, wc = w & 1;
  int lr = lane & 15, lhi = lane >> 4;
  f4_t acc[4][4];
#pragma unroll
  for (int mi = 0; mi < 4; ++mi)
#pragma unroll
    for (int ni = 0; ni < 4; ++ni) acc[mi][ni] = (f4_t){0.f, 0.f, 0.f, 0.f};

  int sub = lane >> 3;
  int scb = ((lane & 7) * 16) ^ (sub << 4);
  auto STAGE = [&](int k0, int buf) {
    char* ab = (char*)As[buf] + (w << 12);
    char* bb2 = (char*)Bs[buf] + (w << 12);
#pragma unroll
    for (int i = 0; i < 4; ++i) {
      int r = 32 * w + 8 * i + sub;
      GLOAD_LDS16((const char*)(A + (size_t)(row0 + r) * K + k0) + scb, ab + (i << 10));
      GLOAD_LDS16((const char*)(BT + (size_t)(col0 + r) * K + k0) + scb, bb2 + (i << 10));
    }
  };

  STAGE(0, 0);

  int nt = K / 64;
  for (int t = 0; t < nt; ++t) {
    int cur = t & 1;
    if (t + 1 < nt) {
      STAGE((t + 1) * 64, cur ^ 1);
      asm volatile("s_waitcnt vmcnt(8)" ::: "memory");
    } else {
      asm volatile("s_waitcnt vmcnt(0)" ::: "memory");
    }
    __builtin_amdgcn_sched_barrier(0);
    __builtin_amdgcn_s_barrier();

    const char* Ac = (const char*)As[cur];
    const char* Bc = (const char*)Bs[cur];
    int rsw = (lr & 7) << 4;
#pragma unroll
    for (int kc = 0; kc < 2; ++kc) {
      bf8_t av[4], bv[4];
#pragma unroll
      for (int mi = 0; mi < 4; ++mi) {
        int row = 64 * wr + 16 * mi + lr;
        av[mi] = *(const bf8_t*)(Ac + row * 128 + ((64 * kc + 16 * lhi) ^ rsw));
      }
#pragma unroll
      for (int ni = 0; ni < 4; ++ni) {
        int row = 64 * wc + 16 * ni + lr;
        bv[ni] = *(const bf8_t*)(Bc + row * 128 + ((64 * kc + 16 * lhi) ^ rsw));
      }
#pragma unroll
      for (int mi = 0; mi < 4; ++mi)
#pragma unroll
        for (int ni = 0; ni < 4; ++ni)
          acc[mi][ni] = __builtin_amdgcn_mfma_f32_16x16x32_bf16(av[mi], bv[ni], acc[mi][ni], 0, 0, 0);
    }
    __builtin_amdgcn_sched_barrier(0);
    __builtin_amdgcn_s_barrier();
  }

#pragma unroll
  for (int mi = 0; mi < 4; ++mi)
#pragma unroll
    for (int ni = 0; ni < 4; ++ni)
#pragma unroll
      for (int r = 0; r < 4; ++r) {
        int row = row0 + 64 * wr + 16 * mi + 4 * lhi + r;
        int col = col0 + 64 * wc + 16 * ni + lr;
        float v = acc[mi][ni][r];
        if (MODE == 0) {
          int which = col / 768;
          int cc2 = col - which * 768;
          int h = cc2 >> 6, dh = cc2 & 63;
          int b = row >> 11, n = row & 2047;  // compacted index
          size_t dst = (((size_t)(b * H_ + h)) * N_ + n) * DH_ + dh;
          short bv2 = f2b(v);
          if (which == 0) Qb[dst] = bv2;
          else if (which == 1) Kb[dst] = bv2;
          else Vb[dst] = bv2;
        } else {
          int j = row & 2047;
          if (j < cn) {
            int n = idx[(row & ~2047) + j];
            Cout[((size_t)(row & ~2047) + n) * ldc + col] = v;
          }
        }
      }
}

// ---------------- Vc[bh][j][dh] -> Vtc[bh][dh][j] (compacted) ----------------
__global__ __launch_bounds__(256) void k_vtrans(const short* __restrict__ V,
                                                const int* __restrict__ cnt,
                                                short* __restrict__ Vt) {
  int bh = blockIdx.y, b = bh / H_;
  int n0 = blockIdx.x * 64;
  int cn = cnt[b];
  int cnpad = (cn + 127) & ~127;
  if (n0 >= cnpad) return;
  __shared__ short T[64][72];
  int tr = threadIdx.x >> 6, tc = threadIdx.x & 63;
  const short* Vp = V + (size_t)bh * N_ * DH_;
  short* Vtp = Vt + (size_t)bh * DH_ * N_;
#pragma unroll
  for (int i = 0; i < 16; ++i) {
    int r = tr + i * 4;
    T[r][tc] = Vp[(size_t)(n0 + r) * DH_ + tc];
  }
  __syncthreads();
#pragma unroll
  for (int i = 0; i < 16; ++i) {
    int r = tr + i * 4;
    Vtp[(size_t)r * N_ + n0 + tc] = T[tc][r];
  }
}

// -------- fill masked rows of out with outrow[b] (fp32) --------
__global__ __launch_bounds__(256) void k_fillout(const int* __restrict__ xmask,
                                                 const float* __restrict__ outrowG,
                                                 float* __restrict__ out) {
  int b = blockIdx.y;
  int n = blockIdx.x * 32 + (threadIdx.x >> 3);
  int cg = threadIdx.x & 7;
  if (xmask[b * N_ + n]) return;
  const float* rp = outrowG + b * D_;
  float* op = out + ((size_t)b * N_ + n) * D_;
#pragma unroll
  for (int it = 0; it < 12; ++it) {
    int c = cg * 8 + it * 64;
    float4 v0 = *(const float4*)(rp + c);
    float4 v1 = *(const float4*)(rp + c + 4);
    *(float4*)(op + c) = v0;
    *(float4*)(op + c + 4) = v1;
  }
}

// -------- flash attention on compacted q/k (swapped-QK^T 32x32) --------
__global__ __launch_bounds__(256, 3) void k_attn(const short* __restrict__ Q,
                                                 const short* __restrict__ Kcg,
                                                 const short* __restrict__ Vtcg,
                                                 const int* __restrict__ cnt,
                                                 short* __restrict__ Aout) {
  int bh = blockIdx.y;
  int b = bh / H_, h = bh - b * H_;
  int cn = cnt[b];
  int nqt = (cn + 127) >> 7;
  if ((int)blockIdx.x >= nqt) return;
  int nkt = (cn + 63) >> 6;
  const short* Qp = Q + (size_t)bh * N_ * DH_;
  const short* Kp = Kcg + (size_t)bh * N_ * DH_;
  const short* Vp = Vtcg + (size_t)bh * DH_ * N_;
  int q0 = blockIdx.x * 128;
  int tid = threadIdx.x, lane = tid & 63, w = tid >> 6;
  int lq = lane & 31, hi = lane >> 5;

  __shared__ char smem[32768];

  int qrow = q0 + 32 * w + lq;

  bf8_t qf[4];
#pragma unroll
  for (int kc = 0; kc < 4; ++kc)
    qf[kc] = *(const bf8_t*)(Qp + (size_t)qrow * DH_ + 16 * kc + 8 * hi);

  short NEGBIG = f2b(-1e30f);
  bf8_t qbf = {hi ? (short)0 : (short)0x3F80, 0, 0, 0, 0, 0, 0, 0};

  f16v acco[2];
#pragma unroll
  for (int i = 0; i < 16; ++i) { acco[0][i] = 0.f; acco[1][i] = 0.f; }
  float m = -1e29f, lsum = 0.f;

  auto STAGE = [&](int key0, int buf) {
    char* kb_ = smem + buf * 16384;
    char* vb_ = kb_ + 8192;
    int row = tid >> 3;
    int cb = (tid & 7) * 16;
    char* lk = kb_ + ((tid >> 6) << 10);
    char* lv = vb_ + ((tid >> 6) << 10);
#pragma unroll
    for (int rr = 0; rr < 2; ++rr) {
      int r2 = row + rr * 32;
      int sw = cb ^ ((r2 & 7) << 4);
      GLOAD_LDS16((const char*)(Kp + (size_t)(key0 + r2) * DH_) + sw, lk + rr * 4096);
      GLOAD_LDS16((const char*)(Vp + (size_t)r2 * N_ + key0) + sw, lv + rr * 4096);
    }
  };

  STAGE(0, 0);
  __syncthreads();

  for (int kt = 0; kt < nkt; ++kt) {
    int cur = kt & 1;
    if (kt + 1 < nkt) STAGE((kt + 1) * 64, cur ^ 1);

    const char* kbase = smem + cur * 16384;
    const char* vbase = kbase + 8192;
    int key0 = kt * 64;

    f16v accs[2];
#pragma unroll
    for (int i = 0; i < 16; ++i) { accs[0][i] = 0.f; accs[1][i] = 0.f; }
    int swz = (lq & 7) << 4;
    __builtin_amdgcn_s_setprio(1);
#pragma unroll
    for (int kc = 0; kc < 4; ++kc) {
      int colb = (32 * kc + 16 * hi) ^ swz;
      bf8_t k0 = *(const bf8_t*)(kbase + lq * 128 + colb);
      bf8_t k1 = *(const bf8_t*)(kbase + (32 + lq) * 128 + colb);
      accs[0] = __builtin_amdgcn_mfma_f32_32x32x16_bf16(k0, qf[kc], accs[0], 0, 0, 0);
      accs[1] = __builtin_amdgcn_mfma_f32_32x32x16_bf16(k1, qf[kc], accs[1], 0, 0, 0);
    }
    __builtin_amdgcn_s_setprio(0);
    if (key0 + 64 > cn) {
      bf8_t bf0 = {(hi || key0 + lq < cn) ? (short)0 : NEGBIG, 0, 0, 0, 0, 0, 0, 0};
      bf8_t bf1 = {(hi || key0 + 32 + lq < cn) ? (short)0 : NEGBIG, 0, 0, 0, 0, 0, 0, 0};
      accs[0] = __builtin_amdgcn_mfma_f32_32x32x16_bf16(bf0, qbf, accs[0], 0, 0, 0);
      accs[1] = __builtin_amdgcn_mfma_f32_32x32x16_bf16(bf1, qbf, accs[1], 0, 0, 0);
    }

    float mx = max3f(accs[0][0], accs[0][1], accs[0][2]);
#pragma unroll
    for (int i = 3; i < 15; i += 2) mx = max3f(mx, accs[0][i], accs[0][i + 1]);
    mx = max3f(mx, accs[0][15], accs[1][0]);
#pragma unroll
    for (int i = 1; i < 15; i += 2) mx = max3f(mx, accs[1][i], accs[1][i + 1]);
    mx = fmaxf(mx, accs[1][15]);
    mx = fmaxf(mx, __shfl_xor(mx, 32));
    if (!__all(mx <= m + 8.f)) {
      float mnew = fmaxf(m, mx);
      float sc = __builtin_amdgcn_exp2f(m - mnew);
      m = mnew;
      lsum *= sc;
#pragma unroll
      for (int i = 0; i < 16; ++i) { acco[0][i] *= sc; acco[1][i] *= sc; }
    }
    float psa[4] = {0.f, 0.f, 0.f, 0.f};
#pragma unroll
    for (int kb2 = 0; kb2 < 2; ++kb2)
#pragma unroll
      for (int r = 0; r < 16; ++r) {
        float p = __builtin_amdgcn_exp2f(accs[kb2][r] - m);
        accs[kb2][r] = p;
        psa[r & 3] += p;
      }
    float ps = (psa[0] + psa[1]) + (psa[2] + psa[3]);
    ps += __shfl_xor(ps, 32);
    lsum += ps;

    __builtin_amdgcn_s_setprio(1);
#pragma unroll
    for (int kc = 0; kc < 4; ++kc) {
      int kb2 = kc >> 1, rb = (kc & 1) * 8;
      unsigned a_ = cvtpk(accs[kb2][rb + 0], accs[kb2][rb + 1]);
      unsigned b_ = cvtpk(accs[kb2][rb + 4], accs[kb2][rb + 5]);
      unsigned c_ = cvtpk(accs[kb2][rb + 2], accs[kb2][rb + 3]);
      unsigned d_ = cvtpk(accs[kb2][rb + 6], accs[kb2][rb + 7]);
      plswap(a_, b_);
      plswap(c_, d_);
      union { i4_t i; bf8_t v; } pu;
      pu.i = (i4_t){(int)a_, (int)c_, (int)b_, (int)d_};
      int colb = (32 * kc + 16 * hi) ^ swz;
      bf8_t v0 = *(const bf8_t*)(vbase + lq * 128 + colb);
      bf8_t v1 = *(const bf8_t*)(vbase + (32 + lq) * 128 + colb);
      acco[0] = __builtin_amdgcn_mfma_f32_32x32x16_bf16(v0, pu.v, acco[0], 0, 0, 0);
      acco[1] = __builtin_amdgcn_mfma_f32_32x32x16_bf16(v1, pu.v, acco[1], 0, 0, 0);
    }
    __builtin_amdgcn_s_setprio(0);

    __syncthreads();
  }
  __syncthreads();

  float inv = 1.f / lsum;
  unsigned* Os = (unsigned*)smem + w * 1152;
#pragma unroll
  for (int dhb = 0; dhb < 2; ++dhb)
#pragma unroll
    for (int r = 0; r < 16; r += 2) {
      unsigned pk = cvtpk(acco[dhb][r] * inv, acco[dhb][r + 1] * inv);
      int colu = 16 * dhb + ((r & 3) >> 1) + 4 * (r >> 2) + 2 * hi;
      Os[lq * 36 + colu] = pk;
    }
#pragma unroll
  for (int it = 0; it < 4; ++it) {
    int q = (lane >> 3) + 8 * it;
    int qr2 = q0 + 32 * w + q;
    if (qr2 < cn) {
      i4_t vv = *(const i4_t*)(Os + q * 36 + 4 * (lane & 7));
      union { i4_t i; bf8_t s; } u2;
      u2.i = vv;
      size_t off = ((size_t)b * N_ + qr2) * D_ + h * DH_ + 8 * (lane & 7);
      *(bf8_t*)(Aout + off) = u2.s;
    }
  }
}

extern "C" void kernel_launch(void* const* d_in, const int* in_sizes, int n_in,
                              void* d_out, int out_size, void* d_ws, size_t ws_size,
                              hipStream_t stream) {
  (void)in_sizes; (void)n_in; (void)out_size; (void)ws_size;
  const float* x  = (const float*)d_in[0];
  const int*   xm = (const int*)d_in[1];
  const float* Wq = (const float*)d_in[2];
  const float* Wk = (const float*)d_in[3];
  const float* Wv = (const float*)d_in[4];
  const float* Wo = (const float*)d_in[5];
  float* out = (float*)d_out;
  char* ws = (char*)d_ws;

  short* xc      = (short*)(ws + 0);
  short* Ao      = (short*)(ws + 0);
  short* WqkvT   = (short*)(ws + 12582912);
  short* WoT     = (short*)(ws + 16121856);
  int*   idxb    = (int*)(ws + 17301504);
  int*   cntb    = (int*)(ws + 17334272);
  float* xpart   = (float*)(ws + 17334528);
  float* vmeanG  = (float*)(ws + 18120960);
  float* outrowG = (float*)(ws + 18133248);
  float* xmeanG  = (float*)(ws + 18145536);
  short* Qb      = (short*)(ws + 18874368);
  short* Kc      = (short*)(ws + 31457280);
  short* Vc      = (short*)(ws + 44040192);
  short* Vtc     = (short*)(ws + 56623104);

  k_maskidx<<<4, 256, 0, stream>>>(xm, idxb, cntb);
  k_xsumA<<<dim3(64, 4), 256, 0, stream>>>(x, xpart);
  k_gatherx<<<dim3(256, 4), 256, 0, stream>>>(x, idxb, cntb, xc);
  k_wtrans<<<dim3(12, 12, 4), 256, 0, stream>>>(Wq, Wk, Wv, Wo, WqkvT, WoT);
  k_gemm<0><<<dim3(18, 64), 256, 0, stream>>>(xc, WqkvT, 768, Qb, Kc, Vc,
                                              nullptr, 0, cntb, nullptr);
  k_vtrans<<<dim3(32, 48), 256, 0, stream>>>(Vc, cntb, Vtc);
  k_xmean<<<dim3(12, 4), 256, 0, stream>>>(xpart, xmeanG);
  k_gemv<<<dim3(12, 4), 256, 0, stream>>>(xmeanG, Wv, vmeanG);
  k_gemv<<<dim3(12, 4), 256, 0, stream>>>(vmeanG, Wo, outrowG);
  k_attn<<<dim3(16, 48), 256, 0, stream>>>(Qb, Kc, Vtc, cntb, Ao);
  k_fillout<<<dim3(64, 4), 256, 0, stream>>>(xm, outrowG, out);
  k_gemm<1><<<dim3(6, 64), 256, 0, stream>>>(Ao, WoT, 768, nullptr, nullptr, nullptr,
                                             out, 768, cntb, idxb);
}